// Round 4
// baseline (666.600 us; speedup 1.0000x reference)
//
#include <hip/hip_runtime.h>

#define N_NODES 100000
#define N_EDGES 3200000
#define F_IN    128
#define H_DIM   32
#define B_GR    256
#define NEG     0.2f

#define SCAN_TILE 1024
#define SCAN_NBLK ((N_NODES + SCAN_TILE - 1) / SCAN_TILE)   // 98

#define N_BIN     8
#define BIN_SZ    (N_NODES / N_BIN)      // 12500 nodes per bin
#define BUILD_NBLK (N_EDGES / 1024)      // 3125 blocks per pass (4 edges/thread)

#define LIN_NODES 16

// ---- monotonic float<->uint encoding for atomicMax on floats ----
__device__ __forceinline__ unsigned fenc(float f) {
    unsigned u = __float_as_uint(f);
    return (u & 0x80000000u) ? ~u : (u | 0x80000000u);
}
__device__ __forceinline__ float fdec(unsigned u) {
    return (u & 0x80000000u) ? __uint_as_float(u & 0x7FFFFFFFu)
                             : __uint_as_float(~u);
}

// K1: xl = x@Wl, xr = x@Wr. 16 nodes/block, 2 nodes/thread, float4 LDS reads.
__global__ __launch_bounds__(256) void k_linear(
    const float* __restrict__ x, const float* __restrict__ Wl,
    const float* __restrict__ Wr, float* __restrict__ xl, float* __restrict__ xr)
{
    __shared__ float Wls[F_IN * H_DIM];           // 16 KB
    __shared__ float Wrs[F_IN * H_DIM];           // 16 KB
    __shared__ float xs[LIN_NODES * F_IN];        // 8 KB
    int t = threadIdx.x;
    for (int i = t; i < F_IN * H_DIM; i += 256) { Wls[i] = Wl[i]; Wrs[i] = Wr[i]; }
    size_t base = (size_t)blockIdx.x * LIN_NODES;
    const float4* xg = (const float4*)(x + base * F_IN);
    float4* xs4 = (float4*)xs;
    xs4[t] = xg[t];
    xs4[t + 256] = xg[t + 256];
    __syncthreads();
    int nl = t >> 5, h = t & 31;
    float al0 = 0.f, ar0 = 0.f, al1 = 0.f, ar1 = 0.f;
    const float4* xa4 = (const float4*)(xs + nl * F_IN);
    const float4* xb4 = (const float4*)(xs + (nl + 8) * F_IN);
    #pragma unroll 8
    for (int f4 = 0; f4 < 32; ++f4) {
        float4 xa = xa4[f4], xb = xb4[f4];
        int fb = f4 * 4;
        float w;
        w = Wls[(fb + 0) * 32 + h]; al0 = fmaf(xa.x, w, al0); al1 = fmaf(xb.x, w, al1);
        w = Wls[(fb + 1) * 32 + h]; al0 = fmaf(xa.y, w, al0); al1 = fmaf(xb.y, w, al1);
        w = Wls[(fb + 2) * 32 + h]; al0 = fmaf(xa.z, w, al0); al1 = fmaf(xb.z, w, al1);
        w = Wls[(fb + 3) * 32 + h]; al0 = fmaf(xa.w, w, al0); al1 = fmaf(xb.w, w, al1);
        w = Wrs[(fb + 0) * 32 + h]; ar0 = fmaf(xa.x, w, ar0); ar1 = fmaf(xb.x, w, ar1);
        w = Wrs[(fb + 1) * 32 + h]; ar0 = fmaf(xa.y, w, ar0); ar1 = fmaf(xb.y, w, ar1);
        w = Wrs[(fb + 2) * 32 + h]; ar0 = fmaf(xa.z, w, ar0); ar1 = fmaf(xb.z, w, ar1);
        w = Wrs[(fb + 3) * 32 + h]; ar0 = fmaf(xa.w, w, ar0); ar1 = fmaf(xb.w, w, ar1);
    }
    size_t n0 = base + nl, n1 = base + nl + 8;
    xl[n0 * 32 + h] = al0; xr[n0 * 32 + h] = ar0;
    xl[n1 * 32 + h] = al1; xr[n1 * 32 + h] = ar1;
}

// K2: histogram of dst
__global__ __launch_bounds__(256) void k_hist(
    const int* __restrict__ dst, int* __restrict__ cnt)
{
    int i = blockIdx.x * 256 + threadIdx.x;          // group of 4 edges
    int4 d = ((const int4*)dst)[i];
    atomicAdd(&cnt[d.x], 1); atomicAdd(&cnt[d.y], 1);
    atomicAdd(&cnt[d.z], 1); atomicAdd(&cnt[d.w], 1);
}

// K3a: per-tile exclusive scan (tile = 1024, 4 elems/thread)
__global__ __launch_bounds__(256) void k_scan_a(
    const int* __restrict__ cnt, int* __restrict__ part, int* __restrict__ bsum)
{
    __shared__ int s[256];
    int b = blockIdx.x, t = threadIdx.x;
    int base = b * SCAN_TILE + t * 4;
    int v[4], sum = 0;
    #pragma unroll
    for (int i = 0; i < 4; ++i) {
        int idx = base + i;
        v[i] = (idx < N_NODES) ? cnt[idx] : 0;
        sum += v[i];
    }
    s[t] = sum; __syncthreads();
    for (int off = 1; off < 256; off <<= 1) {
        int x = (t >= off) ? s[t - off] : 0;
        __syncthreads();
        s[t] += x;
        __syncthreads();
    }
    int run = (t > 0) ? s[t - 1] : 0;
    #pragma unroll
    for (int i = 0; i < 4; ++i) {
        int idx = base + i;
        if (idx < N_NODES) part[idx] = run;
        run += v[i];
    }
    if (t == 255) bsum[b] = s[255];
}

// K3b: scan the 98 block sums (exclusive, in place), single block
__global__ __launch_bounds__(128) void k_scan_b(int* __restrict__ bsum)
{
    __shared__ int s[128];
    int t = threadIdx.x;
    s[t] = (t < SCAN_NBLK) ? bsum[t] : 0; __syncthreads();
    for (int off = 1; off < 128; off <<= 1) {
        int x = (t >= off) ? s[t - off] : 0;
        __syncthreads();
        s[t] += x;
        __syncthreads();
    }
    if (t < SCAN_NBLK) bsum[t] = (t > 0) ? s[t - 1] : 0;
}

// K3c: combine, write rowstart + cursor
__global__ __launch_bounds__(256) void k_scan_c(
    const int* __restrict__ part, const int* __restrict__ bsum,
    int* __restrict__ rowstart, int* __restrict__ cursor)
{
    int i = blockIdx.x * 256 + threadIdx.x;
    if (i < N_NODES) {
        int v = part[i] + bsum[i >> 10];
        rowstart[i] = v;
        cursor[i] = v;
    }
    if (i == 0) rowstart[N_NODES] = N_EDGES;
}

// K4: binned scatter of src ids into dst-sorted CSR.
// bin = blockIdx & 7 -> each bin's srt window + cursor range is handled by a
// single XCD (round-robin blockIdx->XCD), keeping lines XCD-L2-local.
__global__ __launch_bounds__(256) void k_build(
    const int* __restrict__ ei, int* __restrict__ cursor, int* __restrict__ srt)
{
    int pass = blockIdx.x & (N_BIN - 1);
    int blk  = blockIdx.x >> 3;
    int lo = pass * BIN_SZ, hi = lo + BIN_SZ;
    int i = blk * 256 + threadIdx.x;                 // group of 4 edges
    int4 s = ((const int4*)ei)[i];
    int4 d = ((const int4*)(ei + N_EDGES))[i];
    if (d.x >= lo && d.x < hi) { int p = atomicAdd(&cursor[d.x], 1); srt[p] = s.x; }
    if (d.y >= lo && d.y < hi) { int p = atomicAdd(&cursor[d.y], 1); srt[p] = s.y; }
    if (d.z >= lo && d.z < hi) { int p = atomicAdd(&cursor[d.z], 1); srt[p] = s.z; }
    if (d.w >= lo && d.w < hi) { int p = atomicAdd(&cursor[d.w], 1); srt[p] = s.w; }
}

// K5: fused score + online softmax + aggregate + bias + graph max-pool.
// Half-wave (32 lanes) = one node. Chunked two-phase:
//   Phase A (lane = edge): full 32-dim GATv2 dot in-lane, no shuffles.
//   One shfl-max + one rescale + one exp per lane per 32-edge chunk.
//   Phase B (lane = h): broadcast (p,s) via shfl, coalesced gather + fma.
// Self-loop = virtual item at j == e1.
__global__ __launch_bounds__(256) void k_aggregate(
    const int* __restrict__ rowstart, const int* __restrict__ srt,
    const float* __restrict__ xl, const float* __restrict__ xr,
    const float* __restrict__ att, const float* __restrict__ bias,
    const int* __restrict__ batch, unsigned* __restrict__ gu)
{
    __shared__ float lds_xr[8][H_DIM];
    __shared__ float lds_att[H_DIM];
    int t = threadIdx.x;
    int halfg = t >> 5;                 // 0..7: half-wave id in block
    int L = t & 31;                     // lane within half
    int node = blockIdx.x * 8 + halfg;  // grid = N/8 exactly

    if (t < H_DIM) lds_att[t] = att[t];
    lds_xr[halfg][L] = xr[(size_t)node * H_DIM + L];
    __syncthreads();

    const float4* xr4  = (const float4*)lds_xr[halfg];
    const float4* att4 = (const float4*)lds_att;

    int e0 = rowstart[node], e1 = rowstart[node + 1];
    int nitems = e1 - e0 + 1;           // + self-loop

    float m = -1e30f, zL = 0.f, acc = 0.f;

    for (int c = 0; c < nitems; c += 32) {
        int idx = c + L;
        bool valid = idx < nitems;
        int j = e0 + idx;
        int s = node;                    // self item (j == e1) or don't-care
        if (valid && j < e1) s = srt[j];
        float e = -1e30f;
        if (valid) {
            const float4* row = (const float4*)(xl + (size_t)s * H_DIM);
            float e4 = 0.f; float acc0 = 0.f;
            #pragma unroll
            for (int fi = 0; fi < 8; ++fi) {
                float4 xv = row[fi], rv = xr4[fi], av = att4[fi];
                float vx = xv.x + rv.x; vx = fmaxf(vx, NEG * vx);
                float vy = xv.y + rv.y; vy = fmaxf(vy, NEG * vy);
                float vz = xv.z + rv.z; vz = fmaxf(vz, NEG * vz);
                float vw = xv.w + rv.w; vw = fmaxf(vw, NEG * vw);
                acc0 = fmaf(vx, av.x, acc0);
                e4   = fmaf(vy, av.y, e4);
                acc0 = fmaf(vz, av.z, acc0);
                e4   = fmaf(vw, av.w, e4);
            }
            e = acc0 + e4;
        }
        // chunk max (within half-wave)
        float cm = e;
        cm = fmaxf(cm, __shfl_xor(cm, 16));
        cm = fmaxf(cm, __shfl_xor(cm, 8));
        cm = fmaxf(cm, __shfl_xor(cm, 4));
        cm = fmaxf(cm, __shfl_xor(cm, 2));
        cm = fmaxf(cm, __shfl_xor(cm, 1));
        float mn = fmaxf(m, cm);
        float sc = __expf(m - mn);
        zL *= sc; acc *= sc; m = mn;
        float p = valid ? __expf(e - m) : 0.f;
        zL += p;
        int nj = min(32, nitems - c);
        for (int k = 0; k < nj; ++k) {
            float pk = __shfl(p, k, 32);
            int   sk = __shfl(s, k, 32);
            acc = fmaf(pk, xl[(size_t)sk * H_DIM + L], acc);
        }
    }

    float z = zL;
    z += __shfl_xor(z, 16); z += __shfl_xor(z, 8);
    z += __shfl_xor(z, 4);  z += __shfl_xor(z, 2); z += __shfl_xor(z, 1);

    float outv = acc / z + bias[L];
    atomicMax(&gu[batch[node] * H_DIM + L], fenc(outv));
}

// K6: h1 = relu(g @ W1 + b1)
__global__ __launch_bounds__(256) void k_mlp1(
    const unsigned* __restrict__ gu, const float* __restrict__ W1,
    const float* __restrict__ b1, float* __restrict__ h1)
{
    __shared__ float gs[H_DIM];
    int b = blockIdx.x, t = threadIdx.x;
    if (t < H_DIM) gs[t] = fdec(gu[b * H_DIM + t]);
    __syncthreads();
    for (int jj = 0; jj < 4; ++jj) {
        int j = jj * 256 + t;
        float a = b1[j];
        #pragma unroll
        for (int k = 0; k < H_DIM; ++k) a = fmaf(gs[k], W1[k * 1024 + j], a);
        h1[(size_t)b * 1024 + j] = fmaxf(a, 0.f);
    }
}

// K7: h2 = relu(h1 @ W2 + b2), 4 graphs per block
__global__ __launch_bounds__(512) void k_mlp2(
    const float* __restrict__ h1, const float* __restrict__ W2,
    const float* __restrict__ b2, float* __restrict__ h2)
{
    __shared__ float hs[4][1024];
    int b0 = blockIdx.x * 4, t = threadIdx.x;
    for (int r = 0; r < 4; ++r)
        for (int k = t; k < 1024; k += 512) hs[r][k] = h1[(size_t)(b0 + r) * 1024 + k];
    __syncthreads();
    float bb = b2[t];
    float a0 = bb, a1 = bb, a2 = bb, a3 = bb;
    for (int k = 0; k < 1024; ++k) {
        float w = W2[(size_t)k * 512 + t];
        a0 = fmaf(hs[0][k], w, a0);
        a1 = fmaf(hs[1][k], w, a1);
        a2 = fmaf(hs[2][k], w, a2);
        a3 = fmaf(hs[3][k], w, a3);
    }
    h2[(size_t)(b0 + 0) * 512 + t] = fmaxf(a0, 0.f);
    h2[(size_t)(b0 + 1) * 512 + t] = fmaxf(a1, 0.f);
    h2[(size_t)(b0 + 2) * 512 + t] = fmaxf(a2, 0.f);
    h2[(size_t)(b0 + 3) * 512 + t] = fmaxf(a3, 0.f);
}

// K8: out = h2 @ W3 + b3
__global__ __launch_bounds__(256) void k_mlp3(
    const float* __restrict__ h2, const float* __restrict__ W3,
    const float* __restrict__ b3, float* __restrict__ out)
{
    int b = blockIdx.x, t = threadIdx.x;
    int c = t >> 6, lane = t & 63;
    float a = 0.f;
    for (int k = lane; k < 512; k += 64)
        a = fmaf(h2[(size_t)b * 512 + k], W3[k * 4 + c], a);
    for (int off = 32; off; off >>= 1) a += __shfl_down(a, off);
    if (lane == 0) out[b * 4 + c] = a + b3[c];
}

extern "C" void kernel_launch(void* const* d_in, const int* in_sizes, int n_in,
                              void* d_out, int out_size, void* d_ws, size_t ws_size,
                              hipStream_t stream)
{
    const float* x     = (const float*)d_in[0];
    const int*   ei    = (const int*)d_in[1];
    const int*   batch = (const int*)d_in[2];
    const float* Wl    = (const float*)d_in[3];
    const float* Wr    = (const float*)d_in[4];
    const float* att   = (const float*)d_in[5];
    const float* bias  = (const float*)d_in[6];
    const float* W1    = (const float*)d_in[7];
    const float* b1    = (const float*)d_in[8];
    const float* W2    = (const float*)d_in[9];
    const float* b2    = (const float*)d_in[10];
    const float* W3    = (const float*)d_in[11];
    const float* b3    = (const float*)d_in[12];
    float* out = (float*)d_out;

    // workspace layout
    float*    xl       = (float*)d_ws;
    float*    xr       = xl + (size_t)N_NODES * H_DIM;
    int*      srt      = (int*)(xr + (size_t)N_NODES * H_DIM);
    int*      rowstart = srt + N_EDGES;
    int*      cursor   = rowstart + N_NODES + 1;
    int*      part     = cursor + N_NODES;
    int*      bsum     = part + N_NODES;
    int*      cnt      = bsum + 128;              // ---- zeroed region start ----
    unsigned* gu       = (unsigned*)(cnt + N_NODES);
    float*    h1       = (float*)(gu + B_GR * H_DIM);  // ---- zeroed region end ----
    float*    h2       = h1 + (size_t)B_GR * 1024;

    hipMemsetAsync(cnt, 0, (size_t)(N_NODES + B_GR * H_DIM) * sizeof(int), stream);

    k_linear<<<N_NODES / LIN_NODES, 256, 0, stream>>>(x, Wl, Wr, xl, xr);
    k_hist  <<<N_EDGES / 4 / 256, 256, 0, stream>>>(ei + N_EDGES, cnt);
    k_scan_a<<<SCAN_NBLK, 256, 0, stream>>>(cnt, part, bsum);
    k_scan_b<<<1, 128, 0, stream>>>(bsum);
    k_scan_c<<<(N_NODES + 255) / 256, 256, 0, stream>>>(part, bsum, rowstart, cursor);
    k_build <<<N_BIN * BUILD_NBLK, 256, 0, stream>>>(ei, cursor, srt);
    k_aggregate<<<N_NODES / 8, 256, 0, stream>>>(
        rowstart, srt, xl, xr, att, bias, batch, gu);
    k_mlp1<<<B_GR, 256, 0, stream>>>(gu, W1, b1, h1);
    k_mlp2<<<B_GR / 4, 512, 0, stream>>>(h1, W2, b2, h2);
    k_mlp3<<<B_GR, 256, 0, stream>>>(h2, W3, b3, out);
}

// Round 5
// 652.402 us; speedup vs baseline: 1.0218x; 1.0218x over previous
//
#include <hip/hip_runtime.h>

#define N_NODES 100000
#define N_EDGES 3200000
#define F_IN    128
#define H_DIM   32
#define B_GR    256
#define NEG     0.2f

#define SCAN_TILE 1024
#define SCAN_NBLK ((N_NODES + SCAN_TILE - 1) / SCAN_TILE)   // 98

#define N_BIN     8
#define BIN_SZ    (N_NODES / N_BIN)      // 12500 nodes per bin
#define BUILD_NBLK (N_EDGES / 1024)      // 3125 blocks per pass (4 edges/thread)

#define LIN_NODES 16

// ---- monotonic float<->uint encoding for atomicMax on floats ----
__device__ __forceinline__ unsigned fenc(float f) {
    unsigned u = __float_as_uint(f);
    return (u & 0x80000000u) ? ~u : (u | 0x80000000u);
}
__device__ __forceinline__ float fdec(unsigned u) {
    return (u & 0x80000000u) ? __uint_as_float(u & 0x7FFFFFFFu)
                             : __uint_as_float(~u);
}

// K1: xl = x@Wl, xr = x@Wr. 16 nodes/block, 2 nodes/thread, float4 LDS reads.
__global__ __launch_bounds__(256) void k_linear(
    const float* __restrict__ x, const float* __restrict__ Wl,
    const float* __restrict__ Wr, float* __restrict__ xl, float* __restrict__ xr)
{
    __shared__ float Wls[F_IN * H_DIM];           // 16 KB
    __shared__ float Wrs[F_IN * H_DIM];           // 16 KB
    __shared__ float xs[LIN_NODES * F_IN];        // 8 KB
    int t = threadIdx.x;
    for (int i = t; i < F_IN * H_DIM; i += 256) { Wls[i] = Wl[i]; Wrs[i] = Wr[i]; }
    size_t base = (size_t)blockIdx.x * LIN_NODES;
    const float4* xg = (const float4*)(x + base * F_IN);
    float4* xs4 = (float4*)xs;
    xs4[t] = xg[t];
    xs4[t + 256] = xg[t + 256];
    __syncthreads();
    int nl = t >> 5, h = t & 31;
    float al0 = 0.f, ar0 = 0.f, al1 = 0.f, ar1 = 0.f;
    const float4* xa4 = (const float4*)(xs + nl * F_IN);
    const float4* xb4 = (const float4*)(xs + (nl + 8) * F_IN);
    #pragma unroll 8
    for (int f4 = 0; f4 < 32; ++f4) {
        float4 xa = xa4[f4], xb = xb4[f4];
        int fb = f4 * 4;
        float w;
        w = Wls[(fb + 0) * 32 + h]; al0 = fmaf(xa.x, w, al0); al1 = fmaf(xb.x, w, al1);
        w = Wls[(fb + 1) * 32 + h]; al0 = fmaf(xa.y, w, al0); al1 = fmaf(xb.y, w, al1);
        w = Wls[(fb + 2) * 32 + h]; al0 = fmaf(xa.z, w, al0); al1 = fmaf(xb.z, w, al1);
        w = Wls[(fb + 3) * 32 + h]; al0 = fmaf(xa.w, w, al0); al1 = fmaf(xb.w, w, al1);
        w = Wrs[(fb + 0) * 32 + h]; ar0 = fmaf(xa.x, w, ar0); ar1 = fmaf(xb.x, w, ar1);
        w = Wrs[(fb + 1) * 32 + h]; ar0 = fmaf(xa.y, w, ar0); ar1 = fmaf(xb.y, w, ar1);
        w = Wrs[(fb + 2) * 32 + h]; ar0 = fmaf(xa.z, w, ar0); ar1 = fmaf(xb.z, w, ar1);
        w = Wrs[(fb + 3) * 32 + h]; ar0 = fmaf(xa.w, w, ar0); ar1 = fmaf(xb.w, w, ar1);
    }
    size_t n0 = base + nl, n1 = base + nl + 8;
    xl[n0 * 32 + h] = al0; xr[n0 * 32 + h] = ar0;
    xl[n1 * 32 + h] = al1; xr[n1 * 32 + h] = ar1;
}

// K2: histogram of dst
__global__ __launch_bounds__(256) void k_hist(
    const int* __restrict__ dst, int* __restrict__ cnt)
{
    int i = blockIdx.x * 256 + threadIdx.x;          // group of 4 edges
    int4 d = ((const int4*)dst)[i];
    atomicAdd(&cnt[d.x], 1); atomicAdd(&cnt[d.y], 1);
    atomicAdd(&cnt[d.z], 1); atomicAdd(&cnt[d.w], 1);
}

// K3a: per-tile exclusive scan (tile = 1024, 4 elems/thread)
__global__ __launch_bounds__(256) void k_scan_a(
    const int* __restrict__ cnt, int* __restrict__ part, int* __restrict__ bsum)
{
    __shared__ int s[256];
    int b = blockIdx.x, t = threadIdx.x;
    int base = b * SCAN_TILE + t * 4;
    int v[4], sum = 0;
    #pragma unroll
    for (int i = 0; i < 4; ++i) {
        int idx = base + i;
        v[i] = (idx < N_NODES) ? cnt[idx] : 0;
        sum += v[i];
    }
    s[t] = sum; __syncthreads();
    for (int off = 1; off < 256; off <<= 1) {
        int x = (t >= off) ? s[t - off] : 0;
        __syncthreads();
        s[t] += x;
        __syncthreads();
    }
    int run = (t > 0) ? s[t - 1] : 0;
    #pragma unroll
    for (int i = 0; i < 4; ++i) {
        int idx = base + i;
        if (idx < N_NODES) part[idx] = run;
        run += v[i];
    }
    if (t == 255) bsum[b] = s[255];
}

// K3b: scan the 98 block sums (exclusive, in place), single block
__global__ __launch_bounds__(128) void k_scan_b(int* __restrict__ bsum)
{
    __shared__ int s[128];
    int t = threadIdx.x;
    s[t] = (t < SCAN_NBLK) ? bsum[t] : 0; __syncthreads();
    for (int off = 1; off < 128; off <<= 1) {
        int x = (t >= off) ? s[t - off] : 0;
        __syncthreads();
        s[t] += x;
        __syncthreads();
    }
    if (t < SCAN_NBLK) bsum[t] = (t > 0) ? s[t - 1] : 0;
}

// K3c: combine, write rowstart + cursor
__global__ __launch_bounds__(256) void k_scan_c(
    const int* __restrict__ part, const int* __restrict__ bsum,
    int* __restrict__ rowstart, int* __restrict__ cursor)
{
    int i = blockIdx.x * 256 + threadIdx.x;
    if (i < N_NODES) {
        int v = part[i] + bsum[i >> 10];
        rowstart[i] = v;
        cursor[i] = v;
    }
    if (i == 0) rowstart[N_NODES] = N_EDGES;
}

// K4: binned scatter of src ids into dst-sorted CSR. bin = blockIdx & 7.
__global__ __launch_bounds__(256) void k_build(
    const int* __restrict__ ei, int* __restrict__ cursor, int* __restrict__ srt)
{
    int pass = blockIdx.x & (N_BIN - 1);
    int blk  = blockIdx.x >> 3;
    int lo = pass * BIN_SZ, hi = lo + BIN_SZ;
    int i = blk * 256 + threadIdx.x;                 // group of 4 edges
    int4 s = ((const int4*)ei)[i];
    int4 d = ((const int4*)(ei + N_EDGES))[i];
    if (d.x >= lo && d.x < hi) { int p = atomicAdd(&cursor[d.x], 1); srt[p] = s.x; }
    if (d.y >= lo && d.y < hi) { int p = atomicAdd(&cursor[d.y], 1); srt[p] = s.y; }
    if (d.z >= lo && d.z < hi) { int p = atomicAdd(&cursor[d.z], 1); srt[p] = s.z; }
    if (d.w >= lo && d.w < hi) { int p = atomicAdd(&cursor[d.w], 1); srt[p] = s.w; }
}

// K5: fused score + softmax (shift-invariant, no max pass) + aggregate + pool.
// Wave = node, lane = edge. Each lane: gather xl[src] row (regs), in-lane
// 32-dim GATv2 dot, p = exp(e), per-lane 32-float register accumulator.
// One LDS transpose-reduce per node at the end (stride-33 skew, 2 phases).
__global__ __launch_bounds__(256) void k_aggregate(
    const int* __restrict__ rowstart, const int* __restrict__ srt,
    const float* __restrict__ xl, const float* __restrict__ xr,
    const float* __restrict__ att, const float* __restrict__ bias,
    const int* __restrict__ batch, unsigned* __restrict__ gu)
{
    __shared__ float lds_t[2][64 * 33];   // 16.9 KB, 2 wave-slots (phased)
    __shared__ float lds_xr[4][H_DIM];
    __shared__ float lds_att[H_DIM];
    int t = threadIdx.x;
    int w = t >> 6;                // wave 0..3
    int L = t & 63;
    int node = blockIdx.x * 4 + w;

    if (t < H_DIM) lds_att[t] = att[t];
    if (L < H_DIM) lds_xr[w][L] = xr[(size_t)node * H_DIM + L];
    __syncthreads();

    const float4* xr4  = (const float4*)lds_xr[w];
    const float4* att4 = (const float4*)lds_att;

    int e0 = rowstart[node], e1 = rowstart[node + 1];
    int nit = e1 - e0 + 1;          // + self-loop (virtual item at j == e1)
    int smax = max(e1 - 1, 0);

    float zL = 0.f;
    float4 A[8];
    #pragma unroll
    for (int i = 0; i < 8; ++i) A[i] = make_float4(0.f, 0.f, 0.f, 0.f);

    int j0 = e0 + L;
    int s_pre = srt[min(j0, smax)];

    for (int c = 0; c < nit; c += 64) {
        int idx = c + L;
        int j = e0 + idx;
        int s = (j < e1) ? s_pre : node;
        s_pre = srt[min(j + 64, smax)];          // prefetch next chunk

        const float4* rp = (const float4*)(xl + (size_t)s * H_DIM);
        float4 R[8];
        #pragma unroll
        for (int i = 0; i < 8; ++i) R[i] = rp[i];

        float ea = 0.f, eb = 0.f, ec = 0.f, ed = 0.f;
        #pragma unroll
        for (int i = 0; i < 8; ++i) {
            float4 xv = xr4[i];
            float4 av = att4[i];
            float vx = R[i].x + xv.x; vx = fmaxf(vx, vx * NEG); ea = fmaf(vx, av.x, ea);
            float vy = R[i].y + xv.y; vy = fmaxf(vy, vy * NEG); eb = fmaf(vy, av.y, eb);
            float vz = R[i].z + xv.z; vz = fmaxf(vz, vz * NEG); ec = fmaf(vz, av.z, ec);
            float vw = R[i].w + xv.w; vw = fmaxf(vw, vw * NEG); ed = fmaf(vw, av.w, ed);
        }
        float e = (ea + eb) + (ec + ed);
        float p = __expf(fminf(e, 70.f));
        if (idx >= nit) p = 0.f;
        zL += p;
        #pragma unroll
        for (int i = 0; i < 8; ++i) {
            A[i].x = fmaf(p, R[i].x, A[i].x);
            A[i].y = fmaf(p, R[i].y, A[i].y);
            A[i].z = fmaf(p, R[i].z, A[i].z);
            A[i].w = fmaf(p, R[i].w, A[i].w);
        }
    }

    // z: reduce over 64 lanes
    float zz = zL;
    zz += __shfl_xor(zz, 32); zz += __shfl_xor(zz, 16); zz += __shfl_xor(zz, 8);
    zz += __shfl_xor(zz, 4);  zz += __shfl_xor(zz, 2);  zz += __shfl_xor(zz, 1);

    // transpose-reduce A across the 64 lanes, 2 wave-pairs at a time
    int ph = w >> 1, slot = w & 1;
    #pragma unroll
    for (int g = 0; g < 2; ++g) {
        if (ph == g) {
            float* base = &lds_t[slot][0];
            #pragma unroll
            for (int i = 0; i < 8; ++i) {
                base[L * 33 + 4 * i + 0] = A[i].x;
                base[L * 33 + 4 * i + 1] = A[i].y;
                base[L * 33 + 4 * i + 2] = A[i].z;
                base[L * 33 + 4 * i + 3] = A[i].w;
            }
            // lanes 0-31 sum rows 0..31 of column L&31; lanes 32-63 rows 32..63
            int col = L & 31, rbase = (L >> 5) * 32;
            float partial = 0.f;
            #pragma unroll
            for (int k = 0; k < 32; ++k) partial += base[(rbase + k) * 33 + col];
            partial += __shfl_xor(partial, 32);
            if (L < 32) {
                float outv = partial / zz + bias[col];
                atomicMax(&gu[batch[node] * H_DIM + col], fenc(outv));
            }
        }
        __syncthreads();
    }
}

// K6: h1 = relu(g @ W1 + b1)
__global__ __launch_bounds__(256) void k_mlp1(
    const unsigned* __restrict__ gu, const float* __restrict__ W1,
    const float* __restrict__ b1, float* __restrict__ h1)
{
    __shared__ float gs[H_DIM];
    int b = blockIdx.x, t = threadIdx.x;
    if (t < H_DIM) gs[t] = fdec(gu[b * H_DIM + t]);
    __syncthreads();
    for (int jj = 0; jj < 4; ++jj) {
        int j = jj * 256 + t;
        float a = b1[j];
        #pragma unroll
        for (int k = 0; k < H_DIM; ++k) a = fmaf(gs[k], W1[k * 1024 + j], a);
        h1[(size_t)b * 1024 + j] = fmaxf(a, 0.f);
    }
}

// K7: h2 = relu(h1 @ W2 + b2), 4 graphs per block
__global__ __launch_bounds__(512) void k_mlp2(
    const float* __restrict__ h1, const float* __restrict__ W2,
    const float* __restrict__ b2, float* __restrict__ h2)
{
    __shared__ float hs[4][1024];
    int b0 = blockIdx.x * 4, t = threadIdx.x;
    for (int r = 0; r < 4; ++r)
        for (int k = t; k < 1024; k += 512) hs[r][k] = h1[(size_t)(b0 + r) * 1024 + k];
    __syncthreads();
    float bb = b2[t];
    float a0 = bb, a1 = bb, a2 = bb, a3 = bb;
    for (int k = 0; k < 1024; ++k) {
        float w = W2[(size_t)k * 512 + t];
        a0 = fmaf(hs[0][k], w, a0);
        a1 = fmaf(hs[1][k], w, a1);
        a2 = fmaf(hs[2][k], w, a2);
        a3 = fmaf(hs[3][k], w, a3);
    }
    h2[(size_t)(b0 + 0) * 512 + t] = fmaxf(a0, 0.f);
    h2[(size_t)(b0 + 1) * 512 + t] = fmaxf(a1, 0.f);
    h2[(size_t)(b0 + 2) * 512 + t] = fmaxf(a2, 0.f);
    h2[(size_t)(b0 + 3) * 512 + t] = fmaxf(a3, 0.f);
}

// K8: out = h2 @ W3 + b3
__global__ __launch_bounds__(256) void k_mlp3(
    const float* __restrict__ h2, const float* __restrict__ W3,
    const float* __restrict__ b3, float* __restrict__ out)
{
    int b = blockIdx.x, t = threadIdx.x;
    int c = t >> 6, lane = t & 63;
    float a = 0.f;
    for (int k = lane; k < 512; k += 64)
        a = fmaf(h2[(size_t)b * 512 + k], W3[k * 4 + c], a);
    for (int off = 32; off; off >>= 1) a += __shfl_down(a, off);
    if (lane == 0) out[b * 4 + c] = a + b3[c];
}

extern "C" void kernel_launch(void* const* d_in, const int* in_sizes, int n_in,
                              void* d_out, int out_size, void* d_ws, size_t ws_size,
                              hipStream_t stream)
{
    const float* x     = (const float*)d_in[0];
    const int*   ei    = (const int*)d_in[1];
    const int*   batch = (const int*)d_in[2];
    const float* Wl    = (const float*)d_in[3];
    const float* Wr    = (const float*)d_in[4];
    const float* att   = (const float*)d_in[5];
    const float* bias  = (const float*)d_in[6];
    const float* W1    = (const float*)d_in[7];
    const float* b1    = (const float*)d_in[8];
    const float* W2    = (const float*)d_in[9];
    const float* b2    = (const float*)d_in[10];
    const float* W3    = (const float*)d_in[11];
    const float* b3    = (const float*)d_in[12];
    float* out = (float*)d_out;

    // workspace layout
    float*    xl       = (float*)d_ws;
    float*    xr       = xl + (size_t)N_NODES * H_DIM;
    int*      srt      = (int*)(xr + (size_t)N_NODES * H_DIM);
    int*      rowstart = srt + N_EDGES;
    int*      cursor   = rowstart + N_NODES + 1;
    int*      part     = cursor + N_NODES;
    int*      bsum     = part + N_NODES;
    int*      cnt      = bsum + 128;              // ---- zeroed region start ----
    unsigned* gu       = (unsigned*)(cnt + N_NODES);
    float*    h1       = (float*)(gu + B_GR * H_DIM);  // ---- zeroed region end ----
    float*    h2       = h1 + (size_t)B_GR * 1024;

    hipMemsetAsync(cnt, 0, (size_t)(N_NODES + B_GR * H_DIM) * sizeof(int), stream);

    k_linear<<<N_NODES / LIN_NODES, 256, 0, stream>>>(x, Wl, Wr, xl, xr);
    k_hist  <<<N_EDGES / 4 / 256, 256, 0, stream>>>(ei + N_EDGES, cnt);
    k_scan_a<<<SCAN_NBLK, 256, 0, stream>>>(cnt, part, bsum);
    k_scan_b<<<1, 128, 0, stream>>>(bsum);
    k_scan_c<<<(N_NODES + 255) / 256, 256, 0, stream>>>(part, bsum, rowstart, cursor);
    k_build <<<N_BIN * BUILD_NBLK, 256, 0, stream>>>(ei, cursor, srt);
    k_aggregate<<<N_NODES / 4, 256, 0, stream>>>(
        rowstart, srt, xl, xr, att, bias, batch, gu);
    k_mlp1<<<B_GR, 256, 0, stream>>>(gu, W1, b1, h1);
    k_mlp2<<<B_GR / 4, 512, 0, stream>>>(h1, W2, b2, h2);
    k_mlp3<<<B_GR, 256, 0, stream>>>(h2, W3, b3, out);
}

// Round 6
// 589.481 us; speedup vs baseline: 1.1308x; 1.1067x over previous
//
#include <hip/hip_runtime.h>

#define N_NODES 100000
#define N_EDGES 3200000
#define F_IN    128
#define H_DIM   32
#define B_GR    256
#define NEG     0.2f

#define SCAN_TILE 1024
#define SCAN_NBLK ((N_NODES + SCAN_TILE - 1) / SCAN_TILE)   // 98

#define N_BIN    8
#define BIN_SZ   (N_NODES / N_BIN)       // 12500 nodes per bin
#define BIN_CAP  450000                  // mean 400k, +84 sigma margin
#define NB2      ((BIN_CAP + 1023) / 1024)

#define LIN_NODES 16

// ---- monotonic float<->uint encoding for atomicMax on floats ----
__device__ __forceinline__ unsigned fenc(float f) {
    unsigned u = __float_as_uint(f);
    return (u & 0x80000000u) ? ~u : (u | 0x80000000u);
}
__device__ __forceinline__ float fdec(unsigned u) {
    return (u & 0x80000000u) ? __uint_as_float(u & 0x7FFFFFFFu)
                             : __uint_as_float(~u);
}

// K1: xl = x@Wl, xr = x@Wr. 16 nodes/block, 2 nodes/thread, float4 LDS reads.
__global__ __launch_bounds__(256) void k_linear(
    const float* __restrict__ x, const float* __restrict__ Wl,
    const float* __restrict__ Wr, float* __restrict__ xl, float* __restrict__ xr)
{
    __shared__ float Wls[F_IN * H_DIM];           // 16 KB
    __shared__ float Wrs[F_IN * H_DIM];           // 16 KB
    __shared__ float xs[LIN_NODES * F_IN];        // 8 KB
    int t = threadIdx.x;
    for (int i = t; i < F_IN * H_DIM; i += 256) { Wls[i] = Wl[i]; Wrs[i] = Wr[i]; }
    size_t base = (size_t)blockIdx.x * LIN_NODES;
    const float4* xg = (const float4*)(x + base * F_IN);
    float4* xs4 = (float4*)xs;
    xs4[t] = xg[t];
    xs4[t + 256] = xg[t + 256];
    __syncthreads();
    int nl = t >> 5, h = t & 31;
    float al0 = 0.f, ar0 = 0.f, al1 = 0.f, ar1 = 0.f;
    const float4* xa4 = (const float4*)(xs + nl * F_IN);
    const float4* xb4 = (const float4*)(xs + (nl + 8) * F_IN);
    #pragma unroll 8
    for (int f4 = 0; f4 < 32; ++f4) {
        float4 xa = xa4[f4], xb = xb4[f4];
        int fb = f4 * 4;
        float w;
        w = Wls[(fb + 0) * 32 + h]; al0 = fmaf(xa.x, w, al0); al1 = fmaf(xb.x, w, al1);
        w = Wls[(fb + 1) * 32 + h]; al0 = fmaf(xa.y, w, al0); al1 = fmaf(xb.y, w, al1);
        w = Wls[(fb + 2) * 32 + h]; al0 = fmaf(xa.z, w, al0); al1 = fmaf(xb.z, w, al1);
        w = Wls[(fb + 3) * 32 + h]; al0 = fmaf(xa.w, w, al0); al1 = fmaf(xb.w, w, al1);
        w = Wrs[(fb + 0) * 32 + h]; ar0 = fmaf(xa.x, w, ar0); ar1 = fmaf(xb.x, w, ar1);
        w = Wrs[(fb + 1) * 32 + h]; ar0 = fmaf(xa.y, w, ar0); ar1 = fmaf(xb.y, w, ar1);
        w = Wrs[(fb + 2) * 32 + h]; ar0 = fmaf(xa.z, w, ar0); ar1 = fmaf(xb.z, w, ar1);
        w = Wrs[(fb + 3) * 32 + h]; ar0 = fmaf(xa.w, w, ar0); ar1 = fmaf(xb.w, w, ar1);
    }
    size_t n0 = base + nl, n1 = base + nl + 8;
    xl[n0 * 32 + h] = al0; xr[n0 * 32 + h] = ar0;
    xl[n1 * 32 + h] = al1; xr[n1 * 32 + h] = ar1;
}

// K2: histogram of dst
__global__ __launch_bounds__(256) void k_hist(
    const int* __restrict__ dst, int* __restrict__ cnt)
{
    int i = blockIdx.x * 256 + threadIdx.x;          // group of 4 edges
    int4 d = ((const int4*)dst)[i];
    atomicAdd(&cnt[d.x], 1); atomicAdd(&cnt[d.y], 1);
    atomicAdd(&cnt[d.z], 1); atomicAdd(&cnt[d.w], 1);
}

// K3a: per-tile exclusive scan (tile = 1024, 4 elems/thread)
__global__ __launch_bounds__(256) void k_scan_a(
    const int* __restrict__ cnt, int* __restrict__ part, int* __restrict__ bsum)
{
    __shared__ int s[256];
    int b = blockIdx.x, t = threadIdx.x;
    int base = b * SCAN_TILE + t * 4;
    int v[4], sum = 0;
    #pragma unroll
    for (int i = 0; i < 4; ++i) {
        int idx = base + i;
        v[i] = (idx < N_NODES) ? cnt[idx] : 0;
        sum += v[i];
    }
    s[t] = sum; __syncthreads();
    for (int off = 1; off < 256; off <<= 1) {
        int x = (t >= off) ? s[t - off] : 0;
        __syncthreads();
        s[t] += x;
        __syncthreads();
    }
    int run = (t > 0) ? s[t - 1] : 0;
    #pragma unroll
    for (int i = 0; i < 4; ++i) {
        int idx = base + i;
        if (idx < N_NODES) part[idx] = run;
        run += v[i];
    }
    if (t == 255) bsum[b] = s[255];
}

// K3b: scan the 98 block sums (exclusive, in place), single block
__global__ __launch_bounds__(128) void k_scan_b(int* __restrict__ bsum)
{
    __shared__ int s[128];
    int t = threadIdx.x;
    s[t] = (t < SCAN_NBLK) ? bsum[t] : 0; __syncthreads();
    for (int off = 1; off < 128; off <<= 1) {
        int x = (t >= off) ? s[t - off] : 0;
        __syncthreads();
        s[t] += x;
        __syncthreads();
    }
    if (t < SCAN_NBLK) bsum[t] = (t > 0) ? s[t - 1] : 0;
}

// K3c: combine, write rowstart + cursor
__global__ __launch_bounds__(256) void k_scan_c(
    const int* __restrict__ part, const int* __restrict__ bsum,
    int* __restrict__ rowstart, int* __restrict__ cursor)
{
    int i = blockIdx.x * 256 + threadIdx.x;
    if (i < N_NODES) {
        int v = part[i] + bsum[i >> 10];
        rowstart[i] = v;
        cursor[i] = v;
    }
    if (i == 0) rowstart[N_NODES] = N_EDGES;
}

// K4a: single pass over ei, bin edges by dst/BIN_SZ into per-bin staging.
// Packed u32: (dst_local << 17) | src  (src < 2^17, dst_local < 2^14).
// LDS-aggregated bin counters -> 8 global atomics per block.
__global__ __launch_bounds__(256) void k_part(
    const int* __restrict__ ei, int* __restrict__ bcnt, unsigned* __restrict__ binbuf)
{
    __shared__ int lcnt[N_BIN];
    __shared__ int lbase[N_BIN];
    int t = threadIdx.x;
    if (t < N_BIN) lcnt[t] = 0;
    __syncthreads();
    int i = blockIdx.x * 256 + t;                    // group of 4 edges
    int4 s = ((const int4*)ei)[i];
    int4 d = ((const int4*)(ei + N_EDGES))[i];
    int b0 = d.x / BIN_SZ, b1 = d.y / BIN_SZ, b2 = d.z / BIN_SZ, b3 = d.w / BIN_SZ;
    int o0 = atomicAdd(&lcnt[b0], 1);
    int o1 = atomicAdd(&lcnt[b1], 1);
    int o2 = atomicAdd(&lcnt[b2], 1);
    int o3 = atomicAdd(&lcnt[b3], 1);
    __syncthreads();
    if (t < N_BIN) lbase[t] = atomicAdd(&bcnt[t], lcnt[t]);
    __syncthreads();
    binbuf[b0 * BIN_CAP + lbase[b0] + o0] = ((unsigned)(d.x - b0 * BIN_SZ) << 17) | (unsigned)s.x;
    binbuf[b1 * BIN_CAP + lbase[b1] + o1] = ((unsigned)(d.y - b1 * BIN_SZ) << 17) | (unsigned)s.y;
    binbuf[b2 * BIN_CAP + lbase[b2] + o2] = ((unsigned)(d.z - b2 * BIN_SZ) << 17) | (unsigned)s.z;
    binbuf[b3 * BIN_CAP + lbase[b3] + o3] = ((unsigned)(d.w - b3 * BIN_SZ) << 17) | (unsigned)s.w;
}

// K4b: per-bin scatter into the dst-sorted CSR. bin = blockIdx & 7 keeps each
// bin's 1.6 MB srt window + cursor range XCD-L2-local.
__global__ __launch_bounds__(256) void k_scatter(
    const unsigned* __restrict__ binbuf, const int* __restrict__ bcnt,
    int* __restrict__ cursor, int* __restrict__ srt)
{
    int bin = blockIdx.x & (N_BIN - 1);
    int blk = blockIdx.x >> 3;
    int n = bcnt[bin];
    int base = blk * 1024 + threadIdx.x * 4;
    if (base >= n) return;
    const unsigned* bb = binbuf + (size_t)bin * BIN_CAP;
    int lo = bin * BIN_SZ;
    #pragma unroll
    for (int k = 0; k < 4; ++k) {
        int idx = base + k;
        if (idx < n) {
            unsigned e = bb[idx];
            int dloc = e >> 17, src = (int)(e & 0x1FFFFu);
            int p = atomicAdd(&cursor[lo + dloc], 1);
            srt[p] = src;
        }
    }
}

// K5: fused score + softmax (shift-invariant, no max pass) + aggregate + pool.
// Half-wave = node, lane = h. Per edge: coalesced 128 B row load, in-half
// shfl-reduce for the score dot, one exp, two fma. 2-edge unroll per half
// (4 edges in flight per wave), split accumulators, no loop-carried chains.
__global__ __launch_bounds__(256) void k_aggregate(
    const int* __restrict__ rowstart, const int* __restrict__ srt,
    const float* __restrict__ xl, const float* __restrict__ xr,
    const float* __restrict__ att, const float* __restrict__ bias,
    const int* __restrict__ batch, unsigned* __restrict__ gu)
{
    int gt = blockIdx.x * 256 + threadIdx.x;
    int n = gt >> 6;
    int lane = threadIdx.x & 63;
    int h = lane & 31, half = lane >> 5;

    float a   = att[h];
    float xrv = xr[(size_t)n * H_DIM + h];
    float xlv = xl[(size_t)n * H_DIM + h];

    float z0 = 0.f, z1 = 0.f, ac0 = 0.f, ac1 = 0.f;
    {   // self-loop (applied by half 0 only)
        float v = xlv + xrv; v = fmaxf(v, v * NEG);
        float tt = v * a;
        tt += __shfl_xor(tt, 16); tt += __shfl_xor(tt, 8);
        tt += __shfl_xor(tt, 4);  tt += __shfl_xor(tt, 2); tt += __shfl_xor(tt, 1);
        if (half == 0) { float p = __expf(tt); z0 = p; ac0 = p * xlv; }
    }

    int e0 = rowstart[n], e1 = rowstart[n + 1];
    int j = e0 + half;
    for (; j + 2 < e1; j += 4) {
        int sA = srt[j], sB = srt[j + 2];
        float xsA = xl[(size_t)sA * H_DIM + h];
        float xsB = xl[(size_t)sB * H_DIM + h];
        float vA = xsA + xrv; vA = fmaxf(vA, vA * NEG);
        float vB = xsB + xrv; vB = fmaxf(vB, vB * NEG);
        float tA = vA * a, tB = vB * a;
        tA += __shfl_xor(tA, 16); tB += __shfl_xor(tB, 16);
        tA += __shfl_xor(tA, 8);  tB += __shfl_xor(tB, 8);
        tA += __shfl_xor(tA, 4);  tB += __shfl_xor(tB, 4);
        tA += __shfl_xor(tA, 2);  tB += __shfl_xor(tB, 2);
        tA += __shfl_xor(tA, 1);  tB += __shfl_xor(tB, 1);
        float pA = __expf(tA), pB = __expf(tB);
        z0 += pA; z1 += pB;
        ac0 = fmaf(pA, xsA, ac0);
        ac1 = fmaf(pB, xsB, ac1);
    }
    for (; j < e1; j += 2) {
        int s = srt[j];
        float xs = xl[(size_t)s * H_DIM + h];
        float v = xs + xrv; v = fmaxf(v, v * NEG);
        float tt = v * a;
        tt += __shfl_xor(tt, 16); tt += __shfl_xor(tt, 8);
        tt += __shfl_xor(tt, 4);  tt += __shfl_xor(tt, 2); tt += __shfl_xor(tt, 1);
        float p = __expf(tt);
        z0 += p; ac0 = fmaf(p, xs, ac0);
    }

    float z = z0 + z1, acc = ac0 + ac1;
    z += __shfl_xor(z, 32);
    acc += __shfl_xor(acc, 32);
    float outv = acc / z + bias[h];
    if (half == 0) atomicMax(&gu[batch[n] * H_DIM + h], fenc(outv));
}

// K6: h1 = relu(g @ W1 + b1)
__global__ __launch_bounds__(256) void k_mlp1(
    const unsigned* __restrict__ gu, const float* __restrict__ W1,
    const float* __restrict__ b1, float* __restrict__ h1)
{
    __shared__ float gs[H_DIM];
    int b = blockIdx.x, t = threadIdx.x;
    if (t < H_DIM) gs[t] = fdec(gu[b * H_DIM + t]);
    __syncthreads();
    for (int jj = 0; jj < 4; ++jj) {
        int j = jj * 256 + t;
        float a = b1[j];
        #pragma unroll
        for (int k = 0; k < H_DIM; ++k) a = fmaf(gs[k], W1[k * 1024 + j], a);
        h1[(size_t)b * 1024 + j] = fmaxf(a, 0.f);
    }
}

// K7: h2 = relu(h1 @ W2 + b2), 4 graphs per block
__global__ __launch_bounds__(512) void k_mlp2(
    const float* __restrict__ h1, const float* __restrict__ W2,
    const float* __restrict__ b2, float* __restrict__ h2)
{
    __shared__ float hs[4][1024];
    int b0 = blockIdx.x * 4, t = threadIdx.x;
    for (int r = 0; r < 4; ++r)
        for (int k = t; k < 1024; k += 512) hs[r][k] = h1[(size_t)(b0 + r) * 1024 + k];
    __syncthreads();
    float bb = b2[t];
    float a0 = bb, a1 = bb, a2 = bb, a3 = bb;
    for (int k = 0; k < 1024; ++k) {
        float w = W2[(size_t)k * 512 + t];
        a0 = fmaf(hs[0][k], w, a0);
        a1 = fmaf(hs[1][k], w, a1);
        a2 = fmaf(hs[2][k], w, a2);
        a3 = fmaf(hs[3][k], w, a3);
    }
    h2[(size_t)(b0 + 0) * 512 + t] = fmaxf(a0, 0.f);
    h2[(size_t)(b0 + 1) * 512 + t] = fmaxf(a1, 0.f);
    h2[(size_t)(b0 + 2) * 512 + t] = fmaxf(a2, 0.f);
    h2[(size_t)(b0 + 3) * 512 + t] = fmaxf(a3, 0.f);
}

// K8: out = h2 @ W3 + b3
__global__ __launch_bounds__(256) void k_mlp3(
    const float* __restrict__ h2, const float* __restrict__ W3,
    const float* __restrict__ b3, float* __restrict__ out)
{
    int b = blockIdx.x, t = threadIdx.x;
    int c = t >> 6, lane = t & 63;
    float a = 0.f;
    for (int k = lane; k < 512; k += 64)
        a = fmaf(h2[(size_t)b * 512 + k], W3[k * 4 + c], a);
    for (int off = 32; off; off >>= 1) a += __shfl_down(a, off);
    if (lane == 0) out[b * 4 + c] = a + b3[c];
}

extern "C" void kernel_launch(void* const* d_in, const int* in_sizes, int n_in,
                              void* d_out, int out_size, void* d_ws, size_t ws_size,
                              hipStream_t stream)
{
    const float* x     = (const float*)d_in[0];
    const int*   ei    = (const int*)d_in[1];
    const int*   batch = (const int*)d_in[2];
    const float* Wl    = (const float*)d_in[3];
    const float* Wr    = (const float*)d_in[4];
    const float* att   = (const float*)d_in[5];
    const float* bias  = (const float*)d_in[6];
    const float* W1    = (const float*)d_in[7];
    const float* b1    = (const float*)d_in[8];
    const float* W2    = (const float*)d_in[9];
    const float* b2    = (const float*)d_in[10];
    const float* W3    = (const float*)d_in[11];
    const float* b3    = (const float*)d_in[12];
    float* out = (float*)d_out;

    // workspace layout
    float*    xl       = (float*)d_ws;
    float*    xr       = xl + (size_t)N_NODES * H_DIM;
    int*      srt      = (int*)(xr + (size_t)N_NODES * H_DIM);
    int*      rowstart = srt + N_EDGES;
    int*      cursor   = rowstart + N_NODES + 1;
    int*      part     = cursor + N_NODES;
    int*      bsum     = part + N_NODES;
    int*      cnt      = bsum + 128;              // ---- zeroed region start ----
    unsigned* gu       = (unsigned*)(cnt + N_NODES);
    int*      bcnt     = (int*)(gu + B_GR * H_DIM); // ---- zeroed region end ----
    float*    h1       = (float*)(bcnt + N_BIN);
    float*    h2       = h1 + (size_t)B_GR * 1024;
    unsigned* binbuf   = (unsigned*)(h2 + (size_t)B_GR * 512);

    hipMemsetAsync(cnt, 0,
                   (size_t)(N_NODES + B_GR * H_DIM + N_BIN) * sizeof(int), stream);

    k_linear<<<N_NODES / LIN_NODES, 256, 0, stream>>>(x, Wl, Wr, xl, xr);
    k_hist  <<<N_EDGES / 4 / 256, 256, 0, stream>>>(ei + N_EDGES, cnt);
    k_part  <<<N_EDGES / 4 / 256, 256, 0, stream>>>(ei, bcnt, binbuf);
    k_scan_a<<<SCAN_NBLK, 256, 0, stream>>>(cnt, part, bsum);
    k_scan_b<<<1, 128, 0, stream>>>(bsum);
    k_scan_c<<<(N_NODES + 255) / 256, 256, 0, stream>>>(part, bsum, rowstart, cursor);
    k_scatter<<<NB2 * N_BIN, 256, 0, stream>>>(binbuf, bcnt, cursor, srt);
    k_aggregate<<<N_NODES / 4, 256, 0, stream>>>(
        rowstart, srt, xl, xr, att, bias, batch, gu);
    k_mlp1<<<B_GR, 256, 0, stream>>>(gu, W1, b1, h1);
    k_mlp2<<<B_GR / 4, 512, 0, stream>>>(h1, W2, b2, h2);
    k_mlp3<<<B_GR, 256, 0, stream>>>(h2, W3, b3, out);
}